// Round 5
// baseline (1364.166 us; speedup 1.0000x reference)
//
#include <hip/hip_runtime.h>
#include <hip/hip_bf16.h>

#define KS 5
#define K3 125
#define PADW 65

// ---------------------------------------------------------------------------
// Inline basis helpers
// ---------------------------------------------------------------------------
__device__ inline void edge_basis(const float* __restrict__ pseudo, int e,
                                  float* bs, int* ks) {
    float fr[3];
    int bot[3];
#pragma unroll
    for (int d = 0; d < 3; ++d) {
        float v = pseudo[e * 3 + d] * (float)(KS - 1);
        float fl = fminf(floorf(v), (float)(KS - 2));
        fr[d] = v - fl;
        bot[d] = (int)fl;
    }
    const int strides[3] = {1, KS, KS * KS};
#pragma unroll
    for (int s = 0; s < 8; ++s) {
        float b = 1.f;
        int w = 0;
#pragma unroll
        for (int d = 0; d < 3; ++d) {
            int bit = (s >> d) & 1;
            b *= bit ? fr[d] : (1.f - fr[d]);
            w += (bot[d] + bit) * strides[d];
        }
        bs[s] = b;
        ks[s] = w;
    }
}

__device__ inline int edge_bucket(const float* __restrict__ pseudo, int e) {
    int kb = 0;
#pragma unroll
    for (int d = 0; d < 3; ++d) {
        float v = pseudo[e * 3 + d] * (float)(KS - 1);
        int fl = (int)fminf(floorf(v), (float)(KS - 2));
        kb += fl << (2 * d);
    }
    return kb;
}

// ---------------------------------------------------------------------------
// Pass 1: per-level 64-bucket histogram + degree, fused (one grid over E).
// ---------------------------------------------------------------------------
__global__ __launch_bounds__(256) void hist_deg(const float* __restrict__ pseudo,
                                                const int* __restrict__ dst,
                                                int* __restrict__ hist,
                                                float* __restrict__ deg, int E) {
    __shared__ int h[64];
    int t = threadIdx.x;
    if (t < 64) h[t] = 0;
    __syncthreads();
    int e = blockIdx.x * 256 + t;
    if (e < E) {
        atomicAdd(&h[edge_bucket(pseudo, e)], 1);
        atomicAdd(&deg[dst[e]], 1.f);
    }
    __syncthreads();
    if (t < 64 && h[t]) atomicAdd(&hist[t], h[t]);
}

// ---------------------------------------------------------------------------
// Pass 2: bucket layout (tiles of 64 edges, per-bucket padded) + pad fill +
// tile->bucket map. One block of 64 threads per level.
// ---------------------------------------------------------------------------
__global__ void scan_pad64(const int* __restrict__ hist, int* __restrict__ gcur,
                           int* __restrict__ tileOf, int* __restrict__ pack,
                           int tileBase) {
    __shared__ int sh[64];
    int t = threadIdx.x;
    int cnt = hist[t];
    int tiles = (cnt + 63) >> 6;
    sh[t] = tiles;
    __syncthreads();
    for (int d = 1; d < 64; d <<= 1) {
        int v = (t >= d) ? sh[t - d] : 0;
        __syncthreads();
        sh[t] += v;
        __syncthreads();
    }
    int tb = tileBase + sh[t] - tiles;
    int eb = tb * 64;
    gcur[t] = eb;
    for (int q = 0; q < tiles; ++q) tileOf[tb + q] = t;
    for (int idx = eb + cnt; idx < eb + tiles * 64; ++idx) pack[idx] = -1;
}

// ---------------------------------------------------------------------------
// Pass 3: block-local counting sort of EDGES by bucket. 1024 edges / block,
// burst-copied out run-wise (runs of ~16 -> coalesced-ish 64B bursts).
// ---------------------------------------------------------------------------
__global__ __launch_bounds__(256) void scatter_edges(const float* __restrict__ pseudo,
                                                     int* __restrict__ gcur,
                                                     int* __restrict__ pack, int E) {
    __shared__ int h[64], lb[64], gb[64], sh[64];
    __shared__ int sp[1024];
    __shared__ unsigned char skk[1024];
    int t = threadIdx.x;
    int ebase = blockIdx.x * 1024;
    int kbv[4];
    if (t < 64) h[t] = 0;
    __syncthreads();
#pragma unroll
    for (int j = 0; j < 4; ++j) {
        int e = ebase + j * 256 + t;
        if (e < E) {
            kbv[j] = edge_bucket(pseudo, e);
            atomicAdd(&h[kbv[j]], 1);
        } else
            kbv[j] = -1;
    }
    __syncthreads();
    if (t < 64) sh[t] = h[t];
    __syncthreads();
    for (int d = 1; d < 64; d <<= 1) {
        int v = (t < 64 && t >= d) ? sh[t - d] : 0;
        __syncthreads();
        if (t < 64) sh[t] += v;
        __syncthreads();
    }
    if (t < 64) {
        int c = h[t];
        lb[t] = sh[t] - c;
        gb[t] = c ? atomicAdd(&gcur[t], c) : 0;
        h[t] = 0;  // reuse as local cursor
    }
    __syncthreads();
#pragma unroll
    for (int j = 0; j < 4; ++j) {
        int e = ebase + j * 256 + t;
        if (kbv[j] >= 0) {
            int pos = lb[kbv[j]] + atomicAdd(&h[kbv[j]], 1);
            sp[pos] = e;
            skk[pos] = (unsigned char)kbv[j];
        }
    }
    __syncthreads();
    int Pb = E - ebase;
    if (Pb > 1024) Pb = 1024;
    for (int j = t; j < Pb; j += 256) {
        int k = skk[j];
        pack[gb[k] + (j - lb[k])] = sp[j];
    }
}

// ---------------------------------------------------------------------------
// Fused conv1 (in_c = 1)
// ---------------------------------------------------------------------------
__global__ __launch_bounds__(256) void conv1_fused(const float* __restrict__ x,
                                                   const int* __restrict__ src,
                                                   const int* __restrict__ dst,
                                                   const float* __restrict__ pseudo,
                                                   const float* __restrict__ W,
                                                   float* __restrict__ out, int E) {
    const int lane = threadIdx.x & 63;
    const int wid = threadIdx.x >> 6;
    const int sub = lane >> 5;
    const int o = lane & 31;
    int e = (blockIdx.x * 4 + wid) * 2 + sub;
    if (e >= E) return;
    float bs[8];
    int ks[8];
    edge_basis(pseudo, e, bs, ks);
    float acc = 0.f;
#pragma unroll
    for (int s = 0; s < 8; ++s) acc = fmaf(bs[s], W[ks[s] * 32 + o], acc);
    atomicAdd(&out[(size_t)dst[e] * 32 + o], acc * x[src[e]]);
}

// ---------------------------------------------------------------------------
// GEMV over bucket-uniform 64-EDGE tiles. lane = edge. The tile's 8 W slots
// (2x2x2 cube at kbase) are wave-uniform -> scalar loads, broadcast via the
// SGPR operand of v_fmac. Each lane accumulates its edge's full 8-slot sum
// in registers, then ONE coalesced atomic flush per edge (8x fewer atomic
// dwords than per-pair scatter).
// ---------------------------------------------------------------------------
__device__ inline void flush32(float* xT, const float* a, int m, int dn,
                               float* __restrict__ out, int OUT_C, int obase) {
#pragma unroll
    for (int oo = 0; oo < 32; ++oo) xT[oo * PADW + m] = a[oo];
    const int o = m & 31, rh = m >> 5;
    for (int it = 0; it < 32; ++it) {
        int r = 2 * it + rh;
        int dr = __shfl(dn, r);
        if (dr >= 0) atomicAdd(&out[(size_t)dr * OUT_C + obase + o], xT[o * PADW + r]);
    }
}

template <int IN_C, int OUT_C>
__global__ __launch_bounds__(128) void gemv_cube(
    const float* __restrict__ x, const int* __restrict__ src,
    const int* __restrict__ dst, const float* __restrict__ pseudo,
    const int* __restrict__ pack, const int* __restrict__ tileOf,
    const float* __restrict__ W, float* __restrict__ out,
    int tileBase, int nTiles) {
    constexpr int XR = (IN_C > 32) ? IN_C : 32;
    __shared__ float lds[2 * XR * PADW];
    const int wid = threadIdx.x >> 6;
    const int m = threadIdx.x & 63;
    float* xT = &lds[wid * XR * PADW];
    int ti = blockIdx.x * 2 + wid;
    if (ti >= nTiles) return;
    int t = tileBase + ti;
    int kb = tileOf[t];
    if (kb < 0) return;
    kb = __builtin_amdgcn_readfirstlane(kb);
    const int kbase = (kb & 3) + 5 * ((kb >> 2) & 3) + 25 * ((kb >> 4) & 3);
    int e = pack[t * 64 + m];
    float bs[8];
    int sn = 0, dn = -1;
    if (e >= 0) {
        float fr[3];
#pragma unroll
        for (int d = 0; d < 3; ++d) {
            float v = pseudo[e * 3 + d] * (float)(KS - 1);
            float fl = fminf(floorf(v), (float)(KS - 2));
            fr[d] = v - fl;
        }
#pragma unroll
        for (int s = 0; s < 8; ++s) {
            float b = 1.f;
#pragma unroll
            for (int d = 0; d < 3; ++d) b *= ((s >> d) & 1) ? fr[d] : (1.f - fr[d]);
            bs[s] = b;
        }
        sn = src[e];
        dn = dst[e];
    } else {
#pragma unroll
        for (int s = 0; s < 8; ++s) bs[s] = 0.f;
    }
    // stage xT[i][r] = x[src_r][i]
    constexpr int RPI = 64 / IN_C;
    const int i0 = m % IN_C;
    const int rofs = m / IN_C;
    for (int r = rofs; r < 64; r += RPI) {
        int sr = __shfl(sn, r);
        xT[i0 * PADW + r] = x[(size_t)sr * IN_C + i0];
    }
    const float* __restrict__ Wb = W + (size_t)kbase * IN_C * OUT_C;
    constexpr int CUBE = IN_C * OUT_C;
    float a0[32];
#pragma unroll
    for (int oo = 0; oo < 32; ++oo) a0[oo] = 0.f;
    for (int i = 0; i < IN_C; ++i) {
        float xv = xT[i * PADW + m];
#pragma unroll
        for (int s = 0; s < 8; ++s) {
            const int soff = ((s & 1) + 5 * ((s >> 1) & 1) + 25 * ((s >> 2) & 1)) * CUBE;
            const float* __restrict__ Ws = Wb + soff + i * OUT_C;
            float tv = bs[s] * xv;
#pragma unroll
            for (int oo = 0; oo < 32; ++oo) a0[oo] = fmaf(Ws[oo], tv, a0[oo]);
        }
    }
    if constexpr (OUT_C == 64) {
        float a1[32];
#pragma unroll
        for (int oo = 0; oo < 32; ++oo) a1[oo] = 0.f;
        for (int i = 0; i < IN_C; ++i) {
            float xv = xT[i * PADW + m];
#pragma unroll
            for (int s = 0; s < 8; ++s) {
                const int soff = ((s & 1) + 5 * ((s >> 1) & 1) + 25 * ((s >> 2) & 1)) * CUBE;
                const float* __restrict__ Ws = Wb + soff + i * OUT_C + 32;
                float tv = bs[s] * xv;
#pragma unroll
                for (int oo = 0; oo < 32; ++oo) a1[oo] = fmaf(Ws[oo], tv, a1[oo]);
            }
        }
        flush32(xT, a0, m, dn, out, OUT_C, 0);
        flush32(xT, a1, m, dn, out, OUT_C, 32);
    } else {
        flush32(xT, a0, m, dn, out, OUT_C, 0);
    }
}

// ---------------------------------------------------------------------------
// Finalize: out = scatter/max(deg,1) + x@R + B, then ELU. In-place.
// ---------------------------------------------------------------------------
template <int IN_C, int OUT_C>
__global__ __launch_bounds__(256) void finalize_k(
    const float* __restrict__ xin, const float* __restrict__ R,
    const float* __restrict__ B, const float* __restrict__ deg,
    float* __restrict__ out, int n) {
    const int lane = threadIdx.x & 63;
    const int wid = threadIdx.x >> 6;
    constexpr int EPW = 64 / OUT_C;
    const int sub = (EPW == 2) ? (lane >> 5) : 0;
    const int o = lane & (OUT_C - 1);
    int j = (blockIdx.x * (blockDim.x >> 6) + wid) * EPW + sub;
    if (j >= n) return;
    float xv = (o < IN_C) ? xin[j * IN_C + o] : 0.f;
    float acc = B[o];
#pragma unroll 4
    for (int i = 0; i < IN_C; ++i) {
        float xi = __shfl(xv, i, OUT_C);
        acc = fmaf(xi, R[i * OUT_C + o], acc);
    }
    float d = fmaxf(deg[j], 1.f);
    float v = out[j * OUT_C + o] / d + acc;
    out[j * OUT_C + o] = (v > 0.f) ? v : expm1f(v);
}

// ---------------------------------------------------------------------------
// Legacy fallback: edge-centric conv with inline basis (small ws only)
// ---------------------------------------------------------------------------
__global__ void deg_kernel(const int* __restrict__ dst, float* __restrict__ deg, int E) {
    int e = blockIdx.x * blockDim.x + threadIdx.x;
    if (e >= E) return;
    atomicAdd(&deg[dst[e]], 1.0f);
}

template <int IN_C, int OUT_C>
__global__ __launch_bounds__(256) void conv_edges_inline(
    const float* __restrict__ x, const int* __restrict__ src,
    const int* __restrict__ dst, const float* __restrict__ pseudo,
    const float* __restrict__ W, float* __restrict__ out, int E) {
    const int lane = threadIdx.x & 63;
    const int wid = threadIdx.x >> 6;
    constexpr int EPW = 64 / OUT_C;
    const int sub = (EPW == 2) ? (lane >> 5) : 0;
    const int o = lane & (OUT_C - 1);
    long e = (long)(blockIdx.x * (blockDim.x >> 6) + wid) * EPW + sub;
    if (e >= E) return;
    float bs[8];
    int ks[8];
    edge_basis(pseudo, e, bs, ks);
    const int s_ = src[e];
    const int d_ = dst[e];
    float xv = (o < IN_C) ? x[s_ * IN_C + o] : 0.f;
    float acc = 0.f;
#pragma unroll
    for (int s = 0; s < 8; ++s) {
        const float b = bs[s];
        const float* Wk = W + (long)ks[s] * IN_C * OUT_C;
#pragma unroll 4
        for (int i = 0; i < IN_C; ++i) {
            float xi = __shfl(xv, i, OUT_C);
            acc = fmaf(b * xi, Wk[i * OUT_C + o], acc);
        }
    }
    atomicAdd(&out[(long)d_ * OUT_C + o], acc);
}

// ---------------------------------------------------------------------------
// Segment max pooling (monotone uint atomicMax; every slot provably written)
// ---------------------------------------------------------------------------
__global__ void pool_scatter(const float* __restrict__ h, const int* __restrict__ cluster,
                             unsigned* __restrict__ pool, int n, int logC) {
    int idx = blockIdx.x * blockDim.x + threadIdx.x;
    if (idx >= (n << logC)) return;
    int j = idx >> logC;
    int c = idx & ((1 << logC) - 1);
    float f = h[idx];
    int b = __float_as_int(f);
    unsigned enc = (b >= 0) ? ((unsigned)b | 0x80000000u) : ~((unsigned)b);
    atomicMax(&pool[(cluster[j] << logC) + c], enc);
}

__global__ void pool_decode(const unsigned* __restrict__ pool, float* __restrict__ out, int total) {
    int idx = blockIdx.x * blockDim.x + threadIdx.x;
    if (idx >= total) return;
    unsigned u = pool[idx];
    int b = (u & 0x80000000u) ? (int)(u & 0x7FFFFFFFu) : (int)(~u);
    out[idx] = __int_as_float(b);
}

// ---------------------------------------------------------------------------
// Head: mean(64x64) -> fc1 -> fc2 -> log_softmax
// ---------------------------------------------------------------------------
__global__ void head_kernel(const float* __restrict__ h, const float* __restrict__ fc1w,
                            const float* __restrict__ fc1b, const float* __restrict__ fc2w,
                            const float* __restrict__ fc2b, float* __restrict__ out) {
    __shared__ float m[64], t[64], u[10];
    int lane = threadIdx.x;
    float s = 0.f;
    for (int j = 0; j < 64; ++j) s += h[j * 64 + lane];
    m[lane] = s * (1.f / 64.f);
    __syncthreads();
    float a = fc1b[lane];
    for (int i = 0; i < 64; ++i) a = fmaf(m[i], fc1w[i * 64 + lane], a);
    t[lane] = a;
    __syncthreads();
    if (lane < 10) {
        float b = fc2b[lane];
        for (int i = 0; i < 64; ++i) b = fmaf(t[i], fc2w[i * 10 + lane], b);
        u[lane] = b;
    }
    __syncthreads();
    if (lane < 10) {
        float mx = u[0];
        for (int i = 1; i < 10; ++i) mx = fmaxf(mx, u[i]);
        float se = 0.f;
        for (int i = 0; i < 10; ++i) se += expf(u[i] - mx);
        out[lane] = u[lane] - mx - logf(se);
    }
}

// ---------------------------------------------------------------------------
// Host side
// ---------------------------------------------------------------------------
static inline int cdiv(int a, int b) { return (a + b - 1) / b; }

extern "C" void kernel_launch(void* const* d_in, const int* in_sizes, int n_in,
                              void* d_out, int out_size, void* d_ws, size_t ws_size,
                              hipStream_t stream) {
    const float* x = (const float*)d_in[0];
    const int* src[4] = {(const int*)d_in[1], (const int*)d_in[5], (const int*)d_in[9], (const int*)d_in[13]};
    const int* dst[4] = {(const int*)d_in[2], (const int*)d_in[6], (const int*)d_in[10], (const int*)d_in[14]};
    const float* pseudo[4] = {(const float*)d_in[3], (const float*)d_in[7], (const float*)d_in[11], (const float*)d_in[15]};
    const int* cluster[4] = {(const int*)d_in[4], (const int*)d_in[8], (const int*)d_in[12], (const int*)d_in[16]};
    const float* Wp[8], *Rp[8], *Bp[8];
    for (int l = 0; l < 8; ++l) {
        Wp[l] = (const float*)d_in[17 + 3 * l];
        Rp[l] = (const float*)d_in[18 + 3 * l];
        Bp[l] = (const float*)d_in[19 + 3 * l];
    }
    const float* fc1w = (const float*)d_in[41];
    const float* fc1b = (const float*)d_in[42];
    const float* fc2w = (const float*)d_in[43];
    const float* fc2b = (const float*)d_in[44];
    float* outp = (float*)d_out;

    const int NS[5] = {16384, 4096, 1024, 256, 64};
    const int ES[4] = {16384 * 8, 4096 * 8, 1024 * 8, 256 * 8};
    // tile layout: per level, worst case E/64 + 64 tiles of 64 edges
    const int MT[4] = {2048 + 64, 512 + 64, 128 + 64, 32 + 64};
    const int TB_[4] = {0, 2112, 2112 + 576, 2112 + 576 + 192};
    const int TOT_TILES = 2112 + 576 + 192 + 96;  // 2976
    const int DOF[4] = {0, 16384, 16384 + 4096, 16384 + 4096 + 1024};
    const int DTOT = 16384 + 4096 + 1024 + 256;

    char* w = (char*)d_ws;
    auto take = [&](size_t bytes) -> char* {
        char* r = w;
        w += (bytes + 255) & ~(size_t)255;
        return r;
    };
    float* bufA = (float*)take((size_t)NS[0] * 64 * 4);        // 4 MB
    float* bufB = (float*)take((size_t)NS[0] * 64 * 4);        // 4 MB
    unsigned* pool = (unsigned*)take((size_t)NS[1] * 64 * 4);  // 1 MB
    float* degAll = (float*)take((size_t)DTOT * 4);            // 87 KB
    size_t fallbackNeed = (size_t)(w - (char*)d_ws);
    int* hist = (int*)take((size_t)4 * 64 * 4);
    int* gcur = (int*)take((size_t)4 * 64 * 4);
    int* tileOf = (int*)take((size_t)TOT_TILES * 4);
    int* pack = (int*)take((size_t)TOT_TILES * 64 * 4);        // 762 KB
    size_t need = (size_t)(w - (char*)d_ws);
    bool fast = ws_size >= need;

    const int TB = 256;

    if (fast) {
        // ---------- preprocessing: bucket-sort edges, all levels ----------
        hipMemsetAsync(hist, 0, 4 * 64 * 4, stream);
        hipMemsetAsync(tileOf, 0xFF, (size_t)TOT_TILES * 4, stream);
        hipMemsetAsync(degAll, 0, (size_t)DTOT * 4, stream);
        for (int l = 0; l < 4; ++l)
            hist_deg<<<cdiv(ES[l], TB), TB, 0, stream>>>(pseudo[l], dst[l], hist + l * 64,
                                                         degAll + DOF[l], ES[l]);
        for (int l = 0; l < 4; ++l)
            scan_pad64<<<1, 64, 0, stream>>>(hist + l * 64, gcur + l * 64, tileOf, pack, TB_[l]);
        for (int l = 0; l < 4; ++l)
            scatter_edges<<<cdiv(ES[l], 1024), 256, 0, stream>>>(pseudo[l], gcur + l * 64,
                                                                 pack, ES[l]);

        // ---------------- Level 0: conv1 (1->32), conv12 (32->32) ----------
        {
            int E = ES[0], n = NS[0];
            const float* deg = degAll + DOF[0];
            hipMemsetAsync(bufA, 0, (size_t)n * 32 * 4, stream);
            conv1_fused<<<cdiv(E, 8), TB, 0, stream>>>(x, src[0], dst[0], pseudo[0], Wp[0], bufA, E);
            finalize_k<1, 32><<<cdiv(n, 8), TB, 0, stream>>>(x, Rp[0], Bp[0], deg, bufA, n);
            hipMemsetAsync(bufB, 0, (size_t)n * 32 * 4, stream);
            gemv_cube<32, 32><<<cdiv(MT[0], 2), 128, 0, stream>>>(
                bufA, src[0], dst[0], pseudo[0], pack, tileOf, Wp[1], bufB, TB_[0], MT[0]);
            finalize_k<32, 32><<<cdiv(n, 8), TB, 0, stream>>>(bufA, Rp[1], Bp[1], deg, bufB, n);
            hipMemsetAsync(pool, 0, (size_t)NS[1] * 32 * 4, stream);
            pool_scatter<<<cdiv(n * 32, TB), TB, 0, stream>>>(bufB, cluster[0], pool, n, 5);
            pool_decode<<<cdiv(NS[1] * 32, TB), TB, 0, stream>>>(pool, bufA, NS[1] * 32);
        }
        // ---------------- Level 1: conv2 (32->64), conv3 (64->64) ----------
        {
            int E = ES[1], n = NS[1];
            const float* deg = degAll + DOF[1];
            hipMemsetAsync(bufB, 0, (size_t)n * 64 * 4, stream);
            gemv_cube<32, 64><<<cdiv(MT[1], 2), 128, 0, stream>>>(
                bufA, src[1], dst[1], pseudo[1], pack, tileOf, Wp[2], bufB, TB_[1], MT[1]);
            finalize_k<32, 64><<<cdiv(n, 4), TB, 0, stream>>>(bufA, Rp[2], Bp[2], deg, bufB, n);
            hipMemsetAsync(bufA, 0, (size_t)n * 64 * 4, stream);
            gemv_cube<64, 64><<<cdiv(MT[1], 2), 128, 0, stream>>>(
                bufB, src[1], dst[1], pseudo[1], pack, tileOf, Wp[3], bufA, TB_[1], MT[1]);
            finalize_k<64, 64><<<cdiv(n, 4), TB, 0, stream>>>(bufB, Rp[3], Bp[3], deg, bufA, n);
            hipMemsetAsync(pool, 0, (size_t)NS[2] * 64 * 4, stream);
            pool_scatter<<<cdiv(n * 64, TB), TB, 0, stream>>>(bufA, cluster[1], pool, n, 6);
            pool_decode<<<cdiv(NS[2] * 64, TB), TB, 0, stream>>>(pool, bufB, NS[2] * 64);
        }
        // ---------------- Level 2: conv4, conv5 (64->64) -------------------
        {
            int E = ES[2], n = NS[2];
            const float* deg = degAll + DOF[2];
            hipMemsetAsync(bufA, 0, (size_t)n * 64 * 4, stream);
            gemv_cube<64, 64><<<cdiv(MT[2], 2), 128, 0, stream>>>(
                bufB, src[2], dst[2], pseudo[2], pack, tileOf, Wp[4], bufA, TB_[2], MT[2]);
            finalize_k<64, 64><<<cdiv(n, 4), TB, 0, stream>>>(bufB, Rp[4], Bp[4], deg, bufA, n);
            hipMemsetAsync(bufB, 0, (size_t)n * 64 * 4, stream);
            gemv_cube<64, 64><<<cdiv(MT[2], 2), 128, 0, stream>>>(
                bufA, src[2], dst[2], pseudo[2], pack, tileOf, Wp[5], bufB, TB_[2], MT[2]);
            finalize_k<64, 64><<<cdiv(n, 4), TB, 0, stream>>>(bufA, Rp[5], Bp[5], deg, bufB, n);
            hipMemsetAsync(pool, 0, (size_t)NS[3] * 64 * 4, stream);
            pool_scatter<<<cdiv(n * 64, TB), TB, 0, stream>>>(bufB, cluster[2], pool, n, 6);
            pool_decode<<<cdiv(NS[3] * 64, TB), TB, 0, stream>>>(pool, bufA, NS[3] * 64);
        }
        // ---------------- Level 3: conv6, conv7 (64->64) -------------------
        {
            int E = ES[3], n = NS[3];
            const float* deg = degAll + DOF[3];
            hipMemsetAsync(bufB, 0, (size_t)n * 64 * 4, stream);
            gemv_cube<64, 64><<<cdiv(MT[3], 2), 128, 0, stream>>>(
                bufA, src[3], dst[3], pseudo[3], pack, tileOf, Wp[6], bufB, TB_[3], MT[3]);
            finalize_k<64, 64><<<cdiv(n, 4), TB, 0, stream>>>(bufA, Rp[6], Bp[6], deg, bufB, n);
            hipMemsetAsync(bufA, 0, (size_t)n * 64 * 4, stream);
            gemv_cube<64, 64><<<cdiv(MT[3], 2), 128, 0, stream>>>(
                bufB, src[3], dst[3], pseudo[3], pack, tileOf, Wp[7], bufA, TB_[3], MT[3]);
            finalize_k<64, 64><<<cdiv(n, 4), TB, 0, stream>>>(bufB, Rp[7], Bp[7], deg, bufA, n);
            hipMemsetAsync(pool, 0, (size_t)NS[4] * 64 * 4, stream);
            pool_scatter<<<cdiv(n * 64, TB), TB, 0, stream>>>(bufA, cluster[3], pool, n, 6);
            pool_decode<<<cdiv(NS[4] * 64, TB), TB, 0, stream>>>(pool, bufB, NS[4] * 64);
        }
        head_kernel<<<1, 64, 0, stream>>>(bufB, fc1w, fc1b, fc2w, fc2b, outp);
    } else if (ws_size >= fallbackNeed) {
        // ---------------- legacy edge-centric fallback ---------------------
        float* h0 = bufA;
        float* h1 = bufB;
        float* deg = degAll;
        for (int l = 0; l < 4; ++l) {
            int E = ES[l], n = NS[l];
            hipMemsetAsync(deg, 0, n * 4, stream);
            deg_kernel<<<cdiv(E, TB), TB, 0, stream>>>(dst[l], deg, E);
            for (int cc = 0; cc < 2; ++cc) {
                int li = (l == 0) ? cc : 2 * l + cc;
                if (l == 0 && cc == 0) {
                    hipMemsetAsync(h0, 0, (size_t)n * 32 * 4, stream);
                    conv1_fused<<<cdiv(E, 8), TB, 0, stream>>>(x, src[0], dst[0], pseudo[0], Wp[0], h0, E);
                    finalize_k<1, 32><<<cdiv(n, 8), TB, 0, stream>>>(x, Rp[0], Bp[0], deg, h0, n);
                } else {
                    int ic = (l == 0) ? 32 : ((l == 1 && cc == 0) ? 32 : 64);
                    int oc = (l == 0) ? 32 : 64;
                    hipMemsetAsync(h1, 0, (size_t)n * oc * 4, stream);
                    if (ic == 32 && oc == 32) {
                        conv_edges_inline<32, 32><<<cdiv(E, 8), TB, 0, stream>>>(h0, src[l], dst[l], pseudo[l], Wp[li], h1, E);
                        finalize_k<32, 32><<<cdiv(n, 8), TB, 0, stream>>>(h0, Rp[li], Bp[li], deg, h1, n);
                    } else if (ic == 32) {
                        conv_edges_inline<32, 64><<<cdiv(E, 4), TB, 0, stream>>>(h0, src[l], dst[l], pseudo[l], Wp[li], h1, E);
                        finalize_k<32, 64><<<cdiv(n, 4), TB, 0, stream>>>(h0, Rp[li], Bp[li], deg, h1, n);
                    } else {
                        conv_edges_inline<64, 64><<<cdiv(E, 4), TB, 0, stream>>>(h0, src[l], dst[l], pseudo[l], Wp[li], h1, E);
                        finalize_k<64, 64><<<cdiv(n, 4), TB, 0, stream>>>(h0, Rp[li], Bp[li], deg, h1, n);
                    }
                    float* tmp = h0; h0 = h1; h1 = tmp;
                }
            }
            int oc = (l == 0) ? 32 : 64;
            int logC = (l == 0) ? 5 : 6;
            hipMemsetAsync(pool, 0, (size_t)NS[l + 1] * oc * 4, stream);
            pool_scatter<<<cdiv(n * oc, TB), TB, 0, stream>>>(h0, cluster[l], pool, n, logC);
            pool_decode<<<cdiv(NS[l + 1] * oc, TB), TB, 0, stream>>>(pool, h1, NS[l + 1] * oc);
            float* tmp = h0; h0 = h1; h1 = tmp;
        }
        head_kernel<<<1, 64, 0, stream>>>(h0, fc1w, fc1b, fc2w, fc2b, outp);
    }
}

// Round 6
// 975.038 us; speedup vs baseline: 1.3991x; 1.3991x over previous
//
#include <hip/hip_runtime.h>
#include <hip/hip_bf16.h>

#define KS 5
#define K3 125
#define PADW 65

// ---------------------------------------------------------------------------
// Inline basis helpers
// ---------------------------------------------------------------------------
__device__ inline void edge_basis(const float* __restrict__ pseudo, int e,
                                  float* bs, int* ks) {
    float fr[3];
    int bot[3];
#pragma unroll
    for (int d = 0; d < 3; ++d) {
        float v = pseudo[e * 3 + d] * (float)(KS - 1);
        float fl = fminf(floorf(v), (float)(KS - 2));
        fr[d] = v - fl;
        bot[d] = (int)fl;
    }
    const int strides[3] = {1, KS, KS * KS};
#pragma unroll
    for (int s = 0; s < 8; ++s) {
        float b = 1.f;
        int w = 0;
#pragma unroll
        for (int d = 0; d < 3; ++d) {
            int bit = (s >> d) & 1;
            b *= bit ? fr[d] : (1.f - fr[d]);
            w += (bot[d] + bit) * strides[d];
        }
        bs[s] = b;
        ks[s] = w;
    }
}

__device__ inline int edge_bucket(const float* __restrict__ pseudo, int e) {
    int kb = 0;
#pragma unroll
    for (int d = 0; d < 3; ++d) {
        float v = pseudo[e * 3 + d] * (float)(KS - 1);
        int fl = (int)fminf(floorf(v), (float)(KS - 2));
        kb += fl << (2 * d);
    }
    return kb;
}

// ---------------------------------------------------------------------------
// Fused pass 1 (all 4 levels): 64-bucket histogram + degree.
// Block ranges: L0 512, L1 128, L2 32, L3 8 (256 edges/block).
// ---------------------------------------------------------------------------
__global__ __launch_bounds__(256) void hist_deg_all(
    const float* __restrict__ p0, const float* __restrict__ p1,
    const float* __restrict__ p2, const float* __restrict__ p3,
    const int* __restrict__ d0, const int* __restrict__ d1,
    const int* __restrict__ d2, const int* __restrict__ d3,
    int* __restrict__ hist, float* __restrict__ degAll) {
    int b = blockIdx.x;
    int l, lb, E, dof;
    const float* ps;
    const int* ds;
    if (b < 512)      { l = 0; lb = b;       ps = p0; ds = d0; E = 131072; dof = 0; }
    else if (b < 640) { l = 1; lb = b - 512; ps = p1; ds = d1; E = 32768;  dof = 16384; }
    else if (b < 672) { l = 2; lb = b - 640; ps = p2; ds = d2; E = 8192;   dof = 20480; }
    else              { l = 3; lb = b - 672; ps = p3; ds = d3; E = 2048;   dof = 21504; }
    __shared__ int h[64];
    int t = threadIdx.x;
    if (t < 64) h[t] = 0;
    __syncthreads();
    int e = lb * 256 + t;
    if (e < E) {
        atomicAdd(&h[edge_bucket(ps, e)], 1);
        atomicAdd(&degAll[dof + ds[e]], 1.f);
    }
    __syncthreads();
    if (t < 64 && h[t]) atomicAdd(&hist[l * 64 + t], h[t]);
}

// ---------------------------------------------------------------------------
// Fused pass 2: bucket layout per level (blockIdx = level). Tiles of 64
// edges, per-bucket padded; writes cursors, tile->bucket map, pad slots.
// ---------------------------------------------------------------------------
__global__ void scan_pad_all(const int* __restrict__ hist, int* __restrict__ gcur,
                             int* __restrict__ tileOf, int* __restrict__ pack) {
    const int TBv[4] = {0, 2112, 2112 + 576, 2112 + 576 + 192};
    int l = blockIdx.x;
    int tileBase = TBv[l];
    __shared__ int sh[64];
    int t = threadIdx.x;
    int cnt = hist[l * 64 + t];
    int tiles = (cnt + 63) >> 6;
    sh[t] = tiles;
    __syncthreads();
    for (int d = 1; d < 64; d <<= 1) {
        int v = (t >= d) ? sh[t - d] : 0;
        __syncthreads();
        sh[t] += v;
        __syncthreads();
    }
    int tb = tileBase + sh[t] - tiles;
    int eb = tb * 64;
    gcur[l * 64 + t] = eb;
    for (int q = 0; q < tiles; ++q) tileOf[tb + q] = t;
    for (int idx = eb + cnt; idx < eb + tiles * 64; ++idx) pack[idx] = -1;
}

// ---------------------------------------------------------------------------
// Fused pass 3: block-local counting sort of edges (1024 edges/block).
// Block ranges: L0 128, L1 32, L2 8, L3 2.
// ---------------------------------------------------------------------------
__global__ __launch_bounds__(256) void scatter_all(
    const float* __restrict__ p0, const float* __restrict__ p1,
    const float* __restrict__ p2, const float* __restrict__ p3,
    int* __restrict__ gcur, int* __restrict__ pack) {
    int b = blockIdx.x;
    int l, lb, E;
    const float* ps;
    if (b < 128)      { l = 0; lb = b;       ps = p0; E = 131072; }
    else if (b < 160) { l = 1; lb = b - 128; ps = p1; E = 32768; }
    else if (b < 168) { l = 2; lb = b - 160; ps = p2; E = 8192; }
    else              { l = 3; lb = b - 168; ps = p3; E = 2048; }
    int* gc = gcur + l * 64;
    __shared__ int h[64], lbk[64], gb[64], sh[64];
    __shared__ int sp[1024];
    __shared__ unsigned char skk[1024];
    int t = threadIdx.x;
    int ebase = lb * 1024;
    int kbv[4];
    if (t < 64) h[t] = 0;
    __syncthreads();
#pragma unroll
    for (int j = 0; j < 4; ++j) {
        int e = ebase + j * 256 + t;
        if (e < E) {
            kbv[j] = edge_bucket(ps, e);
            atomicAdd(&h[kbv[j]], 1);
        } else
            kbv[j] = -1;
    }
    __syncthreads();
    if (t < 64) sh[t] = h[t];
    __syncthreads();
    for (int d = 1; d < 64; d <<= 1) {
        int v = (t < 64 && t >= d) ? sh[t - d] : 0;
        __syncthreads();
        if (t < 64) sh[t] += v;
        __syncthreads();
    }
    if (t < 64) {
        int c = h[t];
        lbk[t] = sh[t] - c;
        gb[t] = c ? atomicAdd(&gc[t], c) : 0;
        h[t] = 0;
    }
    __syncthreads();
#pragma unroll
    for (int j = 0; j < 4; ++j) {
        int e = ebase + j * 256 + t;
        if (kbv[j] >= 0) {
            int pos = lbk[kbv[j]] + atomicAdd(&h[kbv[j]], 1);
            sp[pos] = e;
            skk[pos] = (unsigned char)kbv[j];
        }
    }
    __syncthreads();
    int Pb = E - ebase;
    if (Pb > 1024) Pb = 1024;
    for (int j = t; j < Pb; j += 256) {
        int k = skk[j];
        pack[gb[k] + (j - lbk[k])] = sp[j];
    }
}

// ---------------------------------------------------------------------------
// Fused conv1 (in_c = 1)
// ---------------------------------------------------------------------------
__global__ __launch_bounds__(256) void conv1_fused(const float* __restrict__ x,
                                                   const int* __restrict__ src,
                                                   const int* __restrict__ dst,
                                                   const float* __restrict__ pseudo,
                                                   const float* __restrict__ W,
                                                   float* __restrict__ out, int E) {
    const int lane = threadIdx.x & 63;
    const int wid = threadIdx.x >> 6;
    const int sub = lane >> 5;
    const int o = lane & 31;
    int e = (blockIdx.x * 4 + wid) * 2 + sub;
    if (e >= E) return;
    float bs[8];
    int ks[8];
    edge_basis(pseudo, e, bs, ks);
    float acc = 0.f;
#pragma unroll
    for (int s = 0; s < 8; ++s) acc = fmaf(bs[s], W[ks[s] * 32 + o], acc);
    atomicAdd(&out[(size_t)dst[e] * 32 + o], acc * x[src[e]]);
}

// ---------------------------------------------------------------------------
// Multi-wave cube GEMV: one block per 64-edge bucket-uniform tile.
// NW waves split the work: oc-halves (OUT_C/32 groups) x slot-groups
// (8/NSG slots each). xT staged cooperatively once; each wave accumulates
// its subset in registers; per-wave LDS transpose -> coalesced atomic flush.
// W read via wave-uniform scalar loads (s outer loop => contiguous stream).
// ---------------------------------------------------------------------------
template <int IN_C, int OUT_C, int NW>
__global__ __launch_bounds__(NW * 64) void gemv_cube_mw(
    const float* __restrict__ x, const int* __restrict__ src,
    const int* __restrict__ dst, const float* __restrict__ pseudo,
    const int* __restrict__ pack, const int* __restrict__ tileOf,
    const float* __restrict__ W, float* __restrict__ out, int tileBase) {
    constexpr int OCW = OUT_C / 32;       // oc groups
    constexpr int NSG = NW / OCW;         // slot groups
    constexpr int SPW = 8 / NSG;          // slots per wave
    constexpr int LROWS = (NW * 32 > IN_C) ? NW * 32 : IN_C;
    __shared__ float lds[LROWS * PADW];
    const int tid = threadIdx.x, wid = tid >> 6, m = tid & 63;
    int t = tileBase + blockIdx.x;
    int kb = tileOf[t];
    if (kb < 0) return;  // pad tile: whole block exits (uniform)
    kb = __builtin_amdgcn_readfirstlane(kb);
    const int kbase = (kb & 3) + 5 * ((kb >> 2) & 3) + 25 * ((kb >> 4) & 3);
    int e = pack[t * 64 + m];
    float bs[8];
    int sn = 0, dn = -1;
    if (e >= 0) {
        float fr[3];
#pragma unroll
        for (int d = 0; d < 3; ++d) {
            float v = pseudo[e * 3 + d] * (float)(KS - 1);
            float fl = fminf(floorf(v), (float)(KS - 2));
            fr[d] = v - fl;
        }
#pragma unroll
        for (int s = 0; s < 8; ++s) {
            float b = 1.f;
#pragma unroll
            for (int d = 0; d < 3; ++d) b *= ((s >> d) & 1) ? fr[d] : (1.f - fr[d]);
            bs[s] = b;
        }
        sn = src[e];
        dn = dst[e];
    } else {
#pragma unroll
        for (int s = 0; s < 8; ++s) bs[s] = 0.f;
    }
    // cooperative stage: xT[i][r] = x[src_r][i]; wave wid covers its r-range
    constexpr int RPW = 64 / NW;
    const int i0 = m % IN_C;
    const int rstep = 64 / IN_C;
    for (int r = wid * RPW + m / IN_C; r < (wid + 1) * RPW; r += rstep) {
        int sr = __shfl(sn, r);
        lds[i0 * PADW + r] = x[(size_t)sr * IN_C + i0];
    }
    __syncthreads();
    // compute: this wave's oc-group and slot-group
    const int ocSel = wid & (OCW - 1);
    const int sg = wid / OCW;
    constexpr int CUBE = IN_C * OUT_C;
    const float* __restrict__ Wb = W + (size_t)kbase * CUBE + ocSel * 32;
    float acc[32];
#pragma unroll
    for (int oo = 0; oo < 32; ++oo) acc[oo] = 0.f;
#pragma unroll
    for (int q = 0; q < SPW; ++q) {
        const int s = sg * SPW + q;
        const int soff = ((s & 1) + 5 * ((s >> 1) & 1) + 25 * ((s >> 2) & 1)) * CUBE;
        const float* __restrict__ Ws = Wb + soff;
        const float bsv = bs[s];
        for (int i = 0; i < IN_C; ++i) {
            float tv = bsv * lds[i * PADW + m];
#pragma unroll
            for (int oo = 0; oo < 32; ++oo)
                acc[oo] = fmaf(Ws[i * OUT_C + oo], tv, acc[oo]);
        }
    }
    __syncthreads();  // xT dead; scratch reuse
    // flush: per-wave transpose slice, coalesced 32-lane atomics per edge
    float* sc = &lds[(wid * 32) * PADW];
#pragma unroll
    for (int oo = 0; oo < 32; ++oo) sc[oo * PADW + m] = acc[oo];
    const int o = m & 31, rh = m >> 5;
    for (int it = 0; it < 32; ++it) {
        int r = 2 * it + rh;
        int dr = __shfl(dn, r);
        if (dr >= 0)
            atomicAdd(&out[(size_t)dr * OUT_C + ocSel * 32 + o], sc[o * PADW + r]);
    }
}

// ---------------------------------------------------------------------------
// Edge-centric conv with inline basis (used for L3 + fallback)
// ---------------------------------------------------------------------------
template <int IN_C, int OUT_C>
__global__ __launch_bounds__(256) void conv_edges_inline(
    const float* __restrict__ x, const int* __restrict__ src,
    const int* __restrict__ dst, const float* __restrict__ pseudo,
    const float* __restrict__ W, float* __restrict__ out, int E) {
    const int lane = threadIdx.x & 63;
    const int wid = threadIdx.x >> 6;
    constexpr int EPW = 64 / OUT_C;
    const int sub = (EPW == 2) ? (lane >> 5) : 0;
    const int o = lane & (OUT_C - 1);
    long e = (long)(blockIdx.x * (blockDim.x >> 6) + wid) * EPW + sub;
    if (e >= E) return;
    float bs[8];
    int ks[8];
    edge_basis(pseudo, e, bs, ks);
    const int s_ = src[e];
    const int d_ = dst[e];
    float xv = (o < IN_C) ? x[s_ * IN_C + o] : 0.f;
    float acc = 0.f;
#pragma unroll
    for (int s = 0; s < 8; ++s) {
        const float b = bs[s];
        const float* Wk = W + (long)ks[s] * IN_C * OUT_C;
#pragma unroll 4
        for (int i = 0; i < IN_C; ++i) {
            float xi = __shfl(xv, i, OUT_C);
            acc = fmaf(b * xi, Wk[i * OUT_C + o], acc);
        }
    }
    atomicAdd(&out[(long)d_ * OUT_C + o], acc);
}

__global__ void deg_kernel(const int* __restrict__ dst, float* __restrict__ deg, int E) {
    int e = blockIdx.x * blockDim.x + threadIdx.x;
    if (e >= E) return;
    atomicAdd(&deg[dst[e]], 1.0f);
}

// ---------------------------------------------------------------------------
// Finalize: out = scatter/max(deg,1) + x@R + B, then ELU. In-place.
// ---------------------------------------------------------------------------
template <int IN_C, int OUT_C>
__global__ __launch_bounds__(256) void finalize_k(
    const float* __restrict__ xin, const float* __restrict__ R,
    const float* __restrict__ B, const float* __restrict__ deg,
    float* __restrict__ out, int n) {
    const int lane = threadIdx.x & 63;
    const int wid = threadIdx.x >> 6;
    constexpr int EPW = 64 / OUT_C;
    const int sub = (EPW == 2) ? (lane >> 5) : 0;
    const int o = lane & (OUT_C - 1);
    int j = (blockIdx.x * (blockDim.x >> 6) + wid) * EPW + sub;
    if (j >= n) return;
    float xv = (o < IN_C) ? xin[j * IN_C + o] : 0.f;
    float acc = B[o];
#pragma unroll 4
    for (int i = 0; i < IN_C; ++i) {
        float xi = __shfl(xv, i, OUT_C);
        acc = fmaf(xi, R[i * OUT_C + o], acc);
    }
    float d = fmaxf(deg[j], 1.f);
    float v = out[j * OUT_C + o] / d + acc;
    out[j * OUT_C + o] = (v > 0.f) ? v : expm1f(v);
}

// ---------------------------------------------------------------------------
// Segment max pooling (monotone uint atomicMax; every slot provably written)
// ---------------------------------------------------------------------------
__global__ void pool_scatter(const float* __restrict__ h, const int* __restrict__ cluster,
                             unsigned* __restrict__ pool, int n, int logC) {
    int idx = blockIdx.x * blockDim.x + threadIdx.x;
    if (idx >= (n << logC)) return;
    int j = idx >> logC;
    int c = idx & ((1 << logC) - 1);
    float f = h[idx];
    int b = __float_as_int(f);
    unsigned enc = (b >= 0) ? ((unsigned)b | 0x80000000u) : ~((unsigned)b);
    atomicMax(&pool[(cluster[j] << logC) + c], enc);
}

__global__ void pool_decode(const unsigned* __restrict__ pool, float* __restrict__ out, int total) {
    int idx = blockIdx.x * blockDim.x + threadIdx.x;
    if (idx >= total) return;
    unsigned u = pool[idx];
    int b = (u & 0x80000000u) ? (int)(u & 0x7FFFFFFFu) : (int)(~u);
    out[idx] = __int_as_float(b);
}

// ---------------------------------------------------------------------------
// Head: mean(64x64) -> fc1 -> fc2 -> log_softmax
// ---------------------------------------------------------------------------
__global__ void head_kernel(const float* __restrict__ h, const float* __restrict__ fc1w,
                            const float* __restrict__ fc1b, const float* __restrict__ fc2w,
                            const float* __restrict__ fc2b, float* __restrict__ out) {
    __shared__ float m[64], t[64], u[10];
    int lane = threadIdx.x;
    float s = 0.f;
    for (int j = 0; j < 64; ++j) s += h[j * 64 + lane];
    m[lane] = s * (1.f / 64.f);
    __syncthreads();
    float a = fc1b[lane];
    for (int i = 0; i < 64; ++i) a = fmaf(m[i], fc1w[i * 64 + lane], a);
    t[lane] = a;
    __syncthreads();
    if (lane < 10) {
        float b = fc2b[lane];
        for (int i = 0; i < 64; ++i) b = fmaf(t[i], fc2w[i * 10 + lane], b);
        u[lane] = b;
    }
    __syncthreads();
    if (lane < 10) {
        float mx = u[0];
        for (int i = 1; i < 10; ++i) mx = fmaxf(mx, u[i]);
        float se = 0.f;
        for (int i = 0; i < 10; ++i) se += expf(u[i] - mx);
        out[lane] = u[lane] - mx - logf(se);
    }
}

// ---------------------------------------------------------------------------
// Host side
// ---------------------------------------------------------------------------
static inline int cdiv(int a, int b) { return (a + b - 1) / b; }

extern "C" void kernel_launch(void* const* d_in, const int* in_sizes, int n_in,
                              void* d_out, int out_size, void* d_ws, size_t ws_size,
                              hipStream_t stream) {
    const float* x = (const float*)d_in[0];
    const int* src[4] = {(const int*)d_in[1], (const int*)d_in[5], (const int*)d_in[9], (const int*)d_in[13]};
    const int* dst[4] = {(const int*)d_in[2], (const int*)d_in[6], (const int*)d_in[10], (const int*)d_in[14]};
    const float* pseudo[4] = {(const float*)d_in[3], (const float*)d_in[7], (const float*)d_in[11], (const float*)d_in[15]};
    const int* cluster[4] = {(const int*)d_in[4], (const int*)d_in[8], (const int*)d_in[12], (const int*)d_in[16]};
    const float* Wp[8], *Rp[8], *Bp[8];
    for (int l = 0; l < 8; ++l) {
        Wp[l] = (const float*)d_in[17 + 3 * l];
        Rp[l] = (const float*)d_in[18 + 3 * l];
        Bp[l] = (const float*)d_in[19 + 3 * l];
    }
    const float* fc1w = (const float*)d_in[41];
    const float* fc1b = (const float*)d_in[42];
    const float* fc2w = (const float*)d_in[43];
    const float* fc2b = (const float*)d_in[44];
    float* outp = (float*)d_out;

    const int NS[5] = {16384, 4096, 1024, 256, 64};
    const int ES[4] = {16384 * 8, 4096 * 8, 1024 * 8, 256 * 8};
    const int MT[4] = {2048 + 64, 512 + 64, 128 + 64, 32 + 64};
    const int TB_[4] = {0, 2112, 2112 + 576, 2112 + 576 + 192};
    const int TOT_TILES = 2112 + 576 + 192 + 96;  // 2976
    const int DOF[4] = {0, 16384, 20480, 21504};
    const int DTOT = 21760;

    char* w = (char*)d_ws;
    auto take = [&](size_t bytes) -> char* {
        char* r = w;
        w += (bytes + 255) & ~(size_t)255;
        return r;
    };
    float* bufA = (float*)take((size_t)NS[0] * 64 * 4);
    float* bufB = (float*)take((size_t)NS[0] * 64 * 4);
    unsigned* pool = (unsigned*)take((size_t)NS[1] * 64 * 4);
    size_t fallbackNeed = (size_t)(w - (char*)d_ws) + (size_t)DTOT * 4;
    int* hist = (int*)take((size_t)4 * 64 * 4);        // hist | degAll contiguous
    float* degAll = (float*)take((size_t)DTOT * 4);
    int* gcur = (int*)take((size_t)4 * 64 * 4);
    int* tileOf = (int*)take((size_t)TOT_TILES * 4);
    int* pack = (int*)take((size_t)TOT_TILES * 64 * 4);
    size_t need = (size_t)(w - (char*)d_ws);
    bool fast = ws_size >= need;

    const int TB = 256;

    if (fast) {
        // ---------- fused pre-pass: hist+deg, layout, sort (3 launches) ----
        hipMemsetAsync(hist, 0, ((size_t)4 * 64 + DTOT) * 4 + 256, stream);
        hipMemsetAsync(tileOf, 0xFF, (size_t)TOT_TILES * 4, stream);
        hist_deg_all<<<680, 256, 0, stream>>>(pseudo[0], pseudo[1], pseudo[2], pseudo[3],
                                              dst[0], dst[1], dst[2], dst[3], hist, degAll);
        scan_pad_all<<<4, 64, 0, stream>>>(hist, gcur, tileOf, pack);
        scatter_all<<<170, 256, 0, stream>>>(pseudo[0], pseudo[1], pseudo[2], pseudo[3],
                                             gcur, pack);

        // ---------------- Level 0: conv1 (1->32), conv12 (32->32) ----------
        {
            int E = ES[0], n = NS[0];
            const float* deg = degAll + DOF[0];
            hipMemsetAsync(bufA, 0, (size_t)n * 32 * 4, stream);
            conv1_fused<<<cdiv(E, 8), TB, 0, stream>>>(x, src[0], dst[0], pseudo[0], Wp[0], bufA, E);
            finalize_k<1, 32><<<cdiv(n, 8), TB, 0, stream>>>(x, Rp[0], Bp[0], deg, bufA, n);
            hipMemsetAsync(bufB, 0, (size_t)n * 32 * 4, stream);
            gemv_cube_mw<32, 32, 2><<<MT[0], 128, 0, stream>>>(
                bufA, src[0], dst[0], pseudo[0], pack, tileOf, Wp[1], bufB, TB_[0]);
            finalize_k<32, 32><<<cdiv(n, 8), TB, 0, stream>>>(bufA, Rp[1], Bp[1], deg, bufB, n);
            hipMemsetAsync(pool, 0, (size_t)NS[1] * 32 * 4, stream);
            pool_scatter<<<cdiv(n * 32, TB), TB, 0, stream>>>(bufB, cluster[0], pool, n, 5);
            pool_decode<<<cdiv(NS[1] * 32, TB), TB, 0, stream>>>(pool, bufA, NS[1] * 32);
        }
        // ---------------- Level 1: conv2 (32->64), conv3 (64->64) ----------
        {
            int n = NS[1];
            const float* deg = degAll + DOF[1];
            hipMemsetAsync(bufB, 0, (size_t)n * 64 * 4, stream);
            gemv_cube_mw<32, 64, 4><<<MT[1], 256, 0, stream>>>(
                bufA, src[1], dst[1], pseudo[1], pack, tileOf, Wp[2], bufB, TB_[1]);
            finalize_k<32, 64><<<cdiv(n, 4), TB, 0, stream>>>(bufA, Rp[2], Bp[2], deg, bufB, n);
            hipMemsetAsync(bufA, 0, (size_t)n * 64 * 4, stream);
            gemv_cube_mw<64, 64, 4><<<MT[1], 256, 0, stream>>>(
                bufB, src[1], dst[1], pseudo[1], pack, tileOf, Wp[3], bufA, TB_[1]);
            finalize_k<64, 64><<<cdiv(n, 4), TB, 0, stream>>>(bufB, Rp[3], Bp[3], deg, bufA, n);
            hipMemsetAsync(pool, 0, (size_t)NS[2] * 64 * 4, stream);
            pool_scatter<<<cdiv(n * 64, TB), TB, 0, stream>>>(bufA, cluster[1], pool, n, 6);
            pool_decode<<<cdiv(NS[2] * 64, TB), TB, 0, stream>>>(pool, bufB, NS[2] * 64);
        }
        // ---------------- Level 2: conv4, conv5 (64->64) -------------------
        {
            int n = NS[2];
            const float* deg = degAll + DOF[2];
            hipMemsetAsync(bufA, 0, (size_t)n * 64 * 4, stream);
            gemv_cube_mw<64, 64, 4><<<MT[2], 256, 0, stream>>>(
                bufB, src[2], dst[2], pseudo[2], pack, tileOf, Wp[4], bufA, TB_[2]);
            finalize_k<64, 64><<<cdiv(n, 4), TB, 0, stream>>>(bufB, Rp[4], Bp[4], deg, bufA, n);
            hipMemsetAsync(bufB, 0, (size_t)n * 64 * 4, stream);
            gemv_cube_mw<64, 64, 4><<<MT[2], 256, 0, stream>>>(
                bufA, src[2], dst[2], pseudo[2], pack, tileOf, Wp[5], bufB, TB_[2]);
            finalize_k<64, 64><<<cdiv(n, 4), TB, 0, stream>>>(bufA, Rp[5], Bp[5], deg, bufB, n);
            hipMemsetAsync(pool, 0, (size_t)NS[3] * 64 * 4, stream);
            pool_scatter<<<cdiv(n * 64, TB), TB, 0, stream>>>(bufB, cluster[2], pool, n, 6);
            pool_decode<<<cdiv(NS[3] * 64, TB), TB, 0, stream>>>(pool, bufA, NS[3] * 64);
        }
        // ---------------- Level 3: conv6, conv7 (64->64), edge-centric -----
        {
            int E = ES[3], n = NS[3];
            const float* deg = degAll + DOF[3];
            hipMemsetAsync(bufB, 0, (size_t)n * 64 * 4, stream);
            conv_edges_inline<64, 64><<<cdiv(E, 4), TB, 0, stream>>>(
                bufA, src[3], dst[3], pseudo[3], Wp[6], bufB, E);
            finalize_k<64, 64><<<cdiv(n, 4), TB, 0, stream>>>(bufA, Rp[6], Bp[6], deg, bufB, n);
            hipMemsetAsync(bufA, 0, (size_t)n * 64 * 4, stream);
            conv_edges_inline<64, 64><<<cdiv(E, 4), TB, 0, stream>>>(
                bufB, src[3], dst[3], pseudo[3], Wp[7], bufA, E);
            finalize_k<64, 64><<<cdiv(n, 4), TB, 0, stream>>>(bufB, Rp[7], Bp[7], deg, bufA, n);
            hipMemsetAsync(pool, 0, (size_t)NS[4] * 64 * 4, stream);
            pool_scatter<<<cdiv(n * 64, TB), TB, 0, stream>>>(bufA, cluster[3], pool, n, 6);
            pool_decode<<<cdiv(NS[4] * 64, TB), TB, 0, stream>>>(pool, bufB, NS[4] * 64);
        }
        head_kernel<<<1, 64, 0, stream>>>(bufB, fc1w, fc1b, fc2w, fc2b, outp);
    } else if (ws_size >= fallbackNeed) {
        // ---------------- legacy edge-centric fallback ---------------------
        float* h0 = bufA;
        float* h1 = bufB;
        float* deg = (float*)hist;  // reuse region
        for (int l = 0; l < 4; ++l) {
            int E = ES[l], n = NS[l];
            hipMemsetAsync(deg, 0, n * 4, stream);
            deg_kernel<<<cdiv(E, TB), TB, 0, stream>>>(dst[l], deg, E);
            for (int cc = 0; cc < 2; ++cc) {
                int li = (l == 0) ? cc : 2 * l + cc;
                if (l == 0 && cc == 0) {
                    hipMemsetAsync(h0, 0, (size_t)n * 32 * 4, stream);
                    conv1_fused<<<cdiv(E, 8), TB, 0, stream>>>(x, src[0], dst[0], pseudo[0], Wp[0], h0, E);
                    finalize_k<1, 32><<<cdiv(n, 8), TB, 0, stream>>>(x, Rp[0], Bp[0], deg, h0, n);
                } else {
                    int ic = (l == 0) ? 32 : ((l == 1 && cc == 0) ? 32 : 64);
                    int oc = (l == 0) ? 32 : 64;
                    hipMemsetAsync(h1, 0, (size_t)n * oc * 4, stream);
                    if (ic == 32 && oc == 32) {
                        conv_edges_inline<32, 32><<<cdiv(E, 8), TB, 0, stream>>>(h0, src[l], dst[l], pseudo[l], Wp[li], h1, E);
                        finalize_k<32, 32><<<cdiv(n, 8), TB, 0, stream>>>(h0, Rp[li], Bp[li], deg, h1, n);
                    } else if (ic == 32) {
                        conv_edges_inline<32, 64><<<cdiv(E, 4), TB, 0, stream>>>(h0, src[l], dst[l], pseudo[l], Wp[li], h1, E);
                        finalize_k<32, 64><<<cdiv(n, 4), TB, 0, stream>>>(h0, Rp[li], Bp[li], deg, h1, n);
                    } else {
                        conv_edges_inline<64, 64><<<cdiv(E, 4), TB, 0, stream>>>(h0, src[l], dst[l], pseudo[l], Wp[li], h1, E);
                        finalize_k<64, 64><<<cdiv(n, 4), TB, 0, stream>>>(h0, Rp[li], Bp[li], deg, h1, n);
                    }
                    float* tmp = h0; h0 = h1; h1 = tmp;
                }
            }
            int oc = (l == 0) ? 32 : 64;
            int logC = (l == 0) ? 5 : 6;
            hipMemsetAsync(pool, 0, (size_t)NS[l + 1] * oc * 4, stream);
            pool_scatter<<<cdiv(n * oc, TB), TB, 0, stream>>>(h0, cluster[l], pool, n, logC);
            pool_decode<<<cdiv(NS[l + 1] * oc, TB), TB, 0, stream>>>(pool, h1, NS[l + 1] * oc);
            float* tmp = h0; h0 = h1; h1 = tmp;
        }
        head_kernel<<<1, 64, 0, stream>>>(h0, fc1w, fc1b, fc2w, fc2b, outp);
    }
}